// Round 7
// baseline (5974.473 us; speedup 1.0000x reference)
//
#include <hip/hip_runtime.h>
#include <hip/hip_bf16.h>
#include <math.h>

#define N_NODES 32768
#define DIM     512
#define NE      524288
#define NL      4
#define NG      128
#define NPG_    256
#define HG_     8
#define CG_     64
#define HT_     4
#define CT_     128
#define FF_     2048
#define AF_     9
#define AV_     64
#define BV_     8
#define OUTD    128

typedef unsigned short u16;
typedef __attribute__((ext_vector_type(8))) short bhalf8;
typedef __attribute__((ext_vector_type(4))) float floatx4;
typedef __attribute__((ext_vector_type(8))) unsigned short u16x8;
typedef __attribute__((ext_vector_type(4))) unsigned short u16x4;

__device__ __forceinline__ u16 f2bf(float f) {
  union { float f; unsigned u; } x; x.f = f;
  unsigned r = x.u + 0x7fffu + ((x.u >> 16) & 1u);   // round-nearest-even
  return (u16)(r >> 16);
}
__device__ __forceinline__ float bf2f(u16 u) {
  union { unsigned u; float f; } x; x.u = ((unsigned)u) << 16; return x.f;
}

#define GL2LDS(gp, lp) __builtin_amdgcn_global_load_lds( \
    (const __attribute__((address_space(1))) unsigned int*)(gp), \
    (__attribute__((address_space(3))) unsigned int*)(lp), 16, 0, 0)

// ---------------------------------------------------------------- encoder (bf16 out)
__global__ __launch_bounds__(128) void atom_enc_kernel(
    const float* __restrict__ emb, const int* __restrict__ x, u16* __restrict__ hb) {
  int n = blockIdx.x;
  int d4 = threadIdx.x;
  const int* xr = x + n * AF_;
  float4 acc = {0.f, 0.f, 0.f, 0.f};
#pragma unroll
  for (int f = 0; f < AF_; ++f) {
    int idx = xr[f];
    const float4 v = *(const float4*)&emb[((size_t)(f * AV_ + idx)) * DIM + 4 * d4];
    acc.x += v.x; acc.y += v.y; acc.z += v.z; acc.w += v.w;
  }
  u16x4 o;
  o[0] = f2bf(acc.x); o[1] = f2bf(acc.y); o[2] = f2bf(acc.z); o[3] = f2bf(acc.w);
  *(u16x4*)&hb[(size_t)n * DIM + 4 * d4] = o;
}

// tab[r, d] = bf16( bond_emb[r, :] @ ge_w[:, d] )  (24 rows, 24KB -> L1)
__global__ __launch_bounds__(512) void bemb_proj_kernel(
    const float* __restrict__ bond_emb, const float* __restrict__ gew, u16* __restrict__ tab) {
  int r = blockIdx.x;
  int d = threadIdx.x;
  const float* a = bond_emb + (size_t)r * DIM;
  float acc = 0.f;
#pragma unroll 8
  for (int kx = 0; kx < DIM; ++kx) acc += a[kx] * gew[(size_t)kx * DIM + d];
  tab[(size_t)r * DIM + d] = f2bf(acc);
}

// ---------------------------------------------------------------- weight cvt+transpose
// W [z][K][N] f32 -> Wt [z][N][K] bf16
__global__ __launch_bounds__(256) void wcvt_kernel(
    const float* __restrict__ W, u16* __restrict__ Wt, int K, int N) {
  __shared__ float t[32][33];
  const size_t mo = (size_t)blockIdx.z * K * N;
  int k0 = blockIdx.y * 32, n0 = blockIdx.x * 32;
  int tx = threadIdx.x & 31, ty = threadIdx.x >> 5;
#pragma unroll
  for (int i = 0; i < 32; i += 8)
    t[ty + i][tx] = W[mo + (size_t)(k0 + ty + i) * N + n0 + tx];
  __syncthreads();
#pragma unroll
  for (int i = 0; i < 32; i += 8)
    Wt[mo + (size_t)(n0 + ty + i) * K + k0 + tx] = f2bf(t[tx][ty + i]);
}

// ---------------------------------------------------------------- MFMA GEMM
// C[M,Nout] = A[M,K](bf16) @ Bt[Nout,K](bf16)^T + bias; 128x128 tile, BK=32,
// 4 waves (2x2), each wave 64x64 via 4x4 frags of 16x16x32.
// vtout: write bf16 transposed per-graph: vt[(row>>8)*512 + col][row&255]
__global__ __launch_bounds__(256) void gemm_mfma_kernel(
    const u16* __restrict__ A, const u16* __restrict__ Bt,
    const float* __restrict__ bias, float* __restrict__ Cf, u16* __restrict__ Cb,
    int K, int Nout, int relu, int bf16out, int vtout) {
  __shared__ __align__(16) u16 As[4096];   // [128 rows][32 k]
  __shared__ __align__(16) u16 Bs[4096];
  const int tid = threadIdx.x;
  const int wave = tid >> 6, lane = tid & 63;
  const int bm = blockIdx.y * 128, bn = blockIdx.x * 128;
  const int wr = wave >> 1, wc = wave & 1;

  const size_t rowA = (size_t)bm + (tid >> 2);
  const size_t rowB = (size_t)bn + (tid >> 2);
  const int gofs = (tid & 3) * 8;
  const u16* pA = A + rowA * K + gofs;
  const u16* pB = Bt + rowB * K + gofs;
  u16* lA0 = &As[wave * 512];
  u16* lB0 = &Bs[wave * 512];
  const size_t skip64 = (size_t)64 * K;

  floatx4 acc[4][4] = {};
  const int r = lane & 15, kg = lane >> 4;
  const int aoff = (wr * 64 + r) * 32 + kg * 8;
  const int boff = (wc * 64 + r) * 32 + kg * 8;

  for (int k0 = 0; k0 < K; k0 += 32) {
    GL2LDS(pA + k0, lA0);
    GL2LDS(pA + skip64 + k0, lA0 + 2048);
    GL2LDS(pB + k0, lB0);
    GL2LDS(pB + skip64 + k0, lB0 + 2048);
    __syncthreads();
    bhalf8 af[4], bg[4];
#pragma unroll
    for (int mi = 0; mi < 4; ++mi) af[mi] = *(const bhalf8*)&As[aoff + mi * 512];
#pragma unroll
    for (int ni = 0; ni < 4; ++ni) bg[ni] = *(const bhalf8*)&Bs[boff + ni * 512];
#pragma unroll
    for (int mi = 0; mi < 4; ++mi)
#pragma unroll
      for (int ni = 0; ni < 4; ++ni)
        acc[mi][ni] = __builtin_amdgcn_mfma_f32_16x16x32_bf16(af[mi], bg[ni], acc[mi][ni], 0, 0, 0);
    __syncthreads();
  }

  // C/D layout: col = lane&15, row = (lane>>4)*4 + reg
  const int rb = (lane >> 4) * 4;
  const int cc = lane & 15;
#pragma unroll
  for (int mi = 0; mi < 4; ++mi) {
#pragma unroll
    for (int ni = 0; ni < 4; ++ni) {
      int gr0 = bm + wr * 64 + mi * 16 + rb;
      int gc = bn + wc * 64 + ni * 16 + cc;
      float bv = bias[gc];
#pragma unroll
      for (int reg = 0; reg < 4; ++reg) {
        int gr = gr0 + reg;
        float v = acc[mi][ni][reg] + bv;
        if (relu) v = fmaxf(v, 0.f);
        if (vtout)        Cb[((size_t)(gr >> 8) * DIM + gc) * NPG_ + (gr & 255)] = f2bf(v);
        else if (bf16out) Cb[(size_t)gr * Nout + gc] = f2bf(v);
        else              Cf[(size_t)gr * Nout + gc] = v;
      }
    }
  }
}

// ---------------------------------------------------------------- MFMA attention S = bf16(QK^T/sqrt(128))
// per local z (0..127), global z = zbase+zl = g*4+h: M=N=256 (grid 2x2), K=128, lda=ldb=512
__global__ __launch_bounds__(256) void attn_s_mfma_kernel(
    const u16* __restrict__ q, const u16* __restrict__ k, u16* __restrict__ S, int zbase) {
  __shared__ __align__(16) u16 As[4096];
  __shared__ __align__(16) u16 Bs[4096];
  const int tid = threadIdx.x;
  const int wave = tid >> 6, lane = tid & 63;
  const int zl = blockIdx.z, z = zbase + zl, g = z >> 2, hh = z & 3;
  const int bm = blockIdx.y * 128, bn = blockIdx.x * 128;
  const int wr = wave >> 1, wc = wave & 1;
  const u16* qg = q + (size_t)g * NPG_ * DIM + hh * CT_;
  const u16* kg2 = k + (size_t)g * NPG_ * DIM + hh * CT_;
  const u16* pA = qg + (size_t)(bm + (tid >> 2)) * DIM + (tid & 3) * 8;
  const u16* pB = kg2 + (size_t)(bn + (tid >> 2)) * DIM + (tid & 3) * 8;
  u16* lA0 = &As[wave * 512];
  u16* lB0 = &Bs[wave * 512];
  const size_t skip64 = (size_t)64 * DIM;
  floatx4 acc[4][4] = {};
  const int r = lane & 15, kg_ = lane >> 4;
  const int aoff = (wr * 64 + r) * 32 + kg_ * 8;
  const int boff = (wc * 64 + r) * 32 + kg_ * 8;
  for (int k0 = 0; k0 < CT_; k0 += 32) {
    GL2LDS(pA + k0, lA0);
    GL2LDS(pA + skip64 + k0, lA0 + 2048);
    GL2LDS(pB + k0, lB0);
    GL2LDS(pB + skip64 + k0, lB0 + 2048);
    __syncthreads();
    bhalf8 af[4], bg[4];
#pragma unroll
    for (int mi = 0; mi < 4; ++mi) af[mi] = *(const bhalf8*)&As[aoff + mi * 512];
#pragma unroll
    for (int ni = 0; ni < 4; ++ni) bg[ni] = *(const bhalf8*)&Bs[boff + ni * 512];
#pragma unroll
    for (int mi = 0; mi < 4; ++mi)
#pragma unroll
      for (int ni = 0; ni < 4; ++ni)
        acc[mi][ni] = __builtin_amdgcn_mfma_f32_16x16x32_bf16(af[mi], bg[ni], acc[mi][ni], 0, 0, 0);
    __syncthreads();
  }
  const float sc = 0.08838834764831845f;   // 1/sqrt(128)
  u16* C = S + (size_t)zl * NPG_ * NPG_;
  const int rb = (lane >> 4) * 4, cc = lane & 15;
#pragma unroll
  for (int mi = 0; mi < 4; ++mi)
#pragma unroll
    for (int ni = 0; ni < 4; ++ni) {
      int gr = bm + wr * 64 + mi * 16 + rb;
      int gc = bn + wc * 64 + ni * 16 + cc;
#pragma unroll
      for (int reg = 0; reg < 4; ++reg)
        C[(size_t)(gr + reg) * NPG_ + gc] = f2bf(acc[mi][ni][reg] * sc);
    }
}

// in-place softmax on bf16 rows (256 wide)
__global__ __launch_bounds__(256) void softmax256_kernel(u16* __restrict__ SP) {
  size_t row = (size_t)blockIdx.x * 4 + (threadIdx.x >> 6);
  int lane = threadIdx.x & 63;
  u16* r = SP + row * NPG_;
  u16x4 v = *(u16x4*)&r[lane * 4];
  float x0 = bf2f(v[0]), x1 = bf2f(v[1]), x2 = bf2f(v[2]), x3 = bf2f(v[3]);
  float m = fmaxf(fmaxf(x0, x1), fmaxf(x2, x3));
#pragma unroll
  for (int off = 32; off; off >>= 1) m = fmaxf(m, __shfl_xor(m, off));
  x0 = expf(x0 - m); x1 = expf(x1 - m); x2 = expf(x2 - m); x3 = expf(x3 - m);
  float s = x0 + x1 + x2 + x3;
#pragma unroll
  for (int off = 32; off; off >>= 1) s += __shfl_xor(s, off);
  float inv = 1.0f / s;
  u16x4 o;
  o[0] = f2bf(x0 * inv); o[1] = f2bf(x1 * inv);
  o[2] = f2bf(x2 * inv); o[3] = f2bf(x3 * inv);
  *(u16x4*)&r[lane * 4] = o;
}

// O[g,qi,h*128+c] = sum_ki P[zl,qi,ki] * vt[g, h*128+c, ki]; per zl: M=256 (grid.y 2), N=128, K=256
__global__ __launch_bounds__(256) void attn_o_mfma_kernel(
    const u16* __restrict__ P, const u16* __restrict__ vt, u16* __restrict__ O, int zbase) {
  __shared__ __align__(16) u16 As[4096];
  __shared__ __align__(16) u16 Bs[4096];
  const int tid = threadIdx.x;
  const int wave = tid >> 6, lane = tid & 63;
  const int zl = blockIdx.z, z = zbase + zl, g = z >> 2, hh = z & 3;
  const int bm = blockIdx.y * 128;
  const int wr = wave >> 1, wc = wave & 1;
  const u16* A = P + (size_t)zl * NPG_ * NPG_;
  const u16* Bt = vt + ((size_t)g * DIM + hh * CT_) * NPG_;
  const u16* pA = A + (size_t)(bm + (tid >> 2)) * NPG_ + (tid & 3) * 8;
  const u16* pB = Bt + (size_t)(tid >> 2) * NPG_ + (tid & 3) * 8;
  u16* lA0 = &As[wave * 512];
  u16* lB0 = &Bs[wave * 512];
  const size_t skip64 = (size_t)64 * NPG_;
  floatx4 acc[4][4] = {};
  const int r = lane & 15, kg_ = lane >> 4;
  const int aoff = (wr * 64 + r) * 32 + kg_ * 8;
  const int boff = (wc * 64 + r) * 32 + kg_ * 8;
  for (int k0 = 0; k0 < NPG_; k0 += 32) {
    GL2LDS(pA + k0, lA0);
    GL2LDS(pA + skip64 + k0, lA0 + 2048);
    GL2LDS(pB + k0, lB0);
    GL2LDS(pB + skip64 + k0, lB0 + 2048);
    __syncthreads();
    bhalf8 af[4], bg[4];
#pragma unroll
    for (int mi = 0; mi < 4; ++mi) af[mi] = *(const bhalf8*)&As[aoff + mi * 512];
#pragma unroll
    for (int ni = 0; ni < 4; ++ni) bg[ni] = *(const bhalf8*)&Bs[boff + ni * 512];
#pragma unroll
    for (int mi = 0; mi < 4; ++mi)
#pragma unroll
      for (int ni = 0; ni < 4; ++ni)
        acc[mi][ni] = __builtin_amdgcn_mfma_f32_16x16x32_bf16(af[mi], bg[ni], acc[mi][ni], 0, 0, 0);
    __syncthreads();
  }
  u16* C = O + ((size_t)g * NPG_) * DIM + hh * CT_;
  const int rb = (lane >> 4) * 4, cc = lane & 15;
#pragma unroll
  for (int mi = 0; mi < 4; ++mi)
#pragma unroll
    for (int ni = 0; ni < 4; ++ni) {
      int gr = bm + wr * 64 + mi * 16 + rb;
      int gc = wc * 64 + ni * 16 + cc;
#pragma unroll
      for (int reg = 0; reg < 4; ++reg)
        C[(size_t)(gr + reg) * DIM + gc] = f2bf(acc[mi][ni][reg]);
    }
}

// ---------------------------------------------------------------- f32 GEMM (final head)
__global__ __launch_bounds__(256) void gemm_bias_kernel(
    const float* __restrict__ A, const float* __restrict__ W,
    const float* __restrict__ bias, float* __restrict__ C,
    int M, int K, int Nout, int relu) {
  __shared__ float As[16][65];
  __shared__ float Bs[16][64];
  const int bm = blockIdx.y * 64;
  const int bn = blockIdx.x * 64;
  const int tid = threadIdx.x;
  const int tx = tid & 15, ty = tid >> 4;
  float acc[4][4] = {};
  for (int k0 = 0; k0 < K; k0 += 16) {
    {
      int row = tid >> 2;
      int kq = (tid & 3) << 2;
      float4 a = *(const float4*)&A[(size_t)(bm + row) * K + k0 + kq];
      As[kq + 0][row] = a.x; As[kq + 1][row] = a.y; As[kq + 2][row] = a.z; As[kq + 3][row] = a.w;
    }
    {
      int krow = tid >> 4;
      int cq = (tid & 15) << 2;
      *(float4*)&Bs[krow][cq] = *(const float4*)&W[(size_t)(k0 + krow) * Nout + bn + cq];
    }
    __syncthreads();
#pragma unroll
    for (int kk = 0; kk < 16; ++kk) {
      float a[4];
#pragma unroll
      for (int i = 0; i < 4; ++i) a[i] = As[kk][ty * 4 + i];
      float4 b4 = *(const float4*)&Bs[kk][tx * 4];
      float b[4] = {b4.x, b4.y, b4.z, b4.w};
#pragma unroll
      for (int i = 0; i < 4; ++i)
#pragma unroll
        for (int j = 0; j < 4; ++j) acc[i][j] = fmaf(a[i], b[j], acc[i][j]);
    }
    __syncthreads();
  }
  float4 bv = *(const float4*)&bias[bn + tx * 4];
#pragma unroll
  for (int i = 0; i < 4; ++i) {
    int row = bm + ty * 4 + i;
    float4 o;
    o.x = acc[i][0] + bv.x; o.y = acc[i][1] + bv.y;
    o.z = acc[i][2] + bv.z; o.w = acc[i][3] + bv.w;
    if (relu) {
      o.x = fmaxf(o.x, 0.f); o.y = fmaxf(o.y, 0.f);
      o.z = fmaxf(o.z, 0.f); o.w = fmaxf(o.w, 0.f);
    }
    *(float4*)&C[(size_t)row * Nout + bn + tx * 4] = o;
  }
}

// ---------------------------------------------------------------- CSR build
__global__ __launch_bounds__(256) void deg_count_kernel(const int* __restrict__ ei, int* __restrict__ deg) {
  int e = blockIdx.x * 256 + threadIdx.x;
  atomicAdd(&deg[ei[NE + e]], 1);
}

__global__ __launch_bounds__(1024) void scan_kernel(const int* __restrict__ deg, int* __restrict__ rp) {
  __shared__ int sums[1024];
  int t = threadIdx.x;
  int base = t * 32;
  int local[32];
  int s = 0;
#pragma unroll
  for (int i = 0; i < 32; ++i) { local[i] = s; s += deg[base + i]; }
  sums[t] = s;
  __syncthreads();
  for (int off = 1; off < 1024; off <<= 1) {
    int other = (t >= off) ? sums[t - off] : 0;
    __syncthreads();
    sums[t] += other;
    __syncthreads();
  }
  int chunk_off = sums[t] - s;
#pragma unroll
  for (int i = 0; i < 32; ++i) rp[base + i] = chunk_off + local[i];
  if (t == 1023) rp[N_NODES] = sums[1023];
}

__global__ __launch_bounds__(256) void scatter_kernel(
    const int* __restrict__ ei, const int* __restrict__ rp,
    int* __restrict__ cur, int* __restrict__ csr) {
  int e = blockIdx.x * 256 + threadIdx.x;
  int d = ei[NE + e];
  int pos = atomicAdd(&cur[d], 1);
  csr[rp[d] + pos] = e;
}

// ---------------------------------------------------------------- edge logits (bf16 q/k/tab)
__global__ __launch_bounds__(256) void edge_logits_kernel(
    const u16* __restrict__ q, const u16* __restrict__ k, const u16* __restrict__ tab,
    const int* __restrict__ ei, const int* __restrict__ ea, float* __restrict__ logits) {
  int e = blockIdx.x * 4 + (threadIdx.x >> 6);
  int lane = threadIdx.x & 63;
  int src = ei[e], dst = ei[NE + e];
  int a0 = ea[e * 3], a1 = ea[e * 3 + 1], a2 = ea[e * 3 + 2];
  const u16x8 qv = *(const u16x8*)&q[(size_t)dst * DIM + lane * 8];
  const u16x8 kv = *(const u16x8*)&k[(size_t)src * DIM + lane * 8];
  const size_t to = (size_t)lane * 8;
  const u16x8 e0 = *(const u16x8*)&tab[(size_t)a0 * DIM + to];
  const u16x8 e1 = *(const u16x8*)&tab[(size_t)(8 + a1) * DIM + to];
  const u16x8 e2 = *(const u16x8*)&tab[(size_t)(16 + a2) * DIM + to];
  float acc = 0.f;
#pragma unroll
  for (int j = 0; j < 8; ++j) {
    float ee = bf2f(e0[j]) + bf2f(e1[j]) + bf2f(e2[j]);
    acc += bf2f(qv[j]) * (bf2f(kv[j]) + ee);
  }
  acc += __shfl_xor(acc, 1);
  acc += __shfl_xor(acc, 2);
  acc += __shfl_xor(acc, 4);
  if ((lane & 7) == 0) logits[(size_t)e * HG_ + (lane >> 3)] = acc * 0.125f;
}

// ---------------------------------------------------------------- edge aggregation (per node)
#define CHUNK 128
__global__ __launch_bounds__(512) void edge_agg_kernel(
    const u16* __restrict__ v, const u16* __restrict__ tab, const float* __restrict__ logits,
    const float* __restrict__ skip, const int* __restrict__ ei, const int* __restrict__ ea,
    const int* __restrict__ rp, const int* __restrict__ csr, u16* __restrict__ hnew) {
  int n = blockIdx.x;
  int d = threadIdx.x;
  int hh = d >> 6;
  int start = rp[n];
  int deg = rp[n + 1] - start;
  __shared__ int s_src[CHUNK];
  __shared__ int s_ea[CHUNK];
  __shared__ int s_eid[CHUNK];
  __shared__ float s_l[CHUNK * HG_];
  float runmax = -3.0e38f, denom = 0.f, accum = 0.f;
  for (int c0 = 0; c0 < deg; c0 += CHUNK) {
    int cnt = min(CHUNK, deg - c0);
    __syncthreads();
    if (d < cnt) {
      int eid = csr[start + c0 + d];
      s_eid[d] = eid;
      s_src[d] = ei[eid];
      s_ea[d] = ea[eid * 3] | (ea[eid * 3 + 1] << 8) | (ea[eid * 3 + 2] << 16);
    }
    __syncthreads();
    for (int j = d; j < cnt * HG_; j += 512)
      s_l[j] = logits[(size_t)s_eid[j >> 3] * HG_ + (j & 7)];
    __syncthreads();
    float cmax = -3.0e38f;
    for (int j = 0; j < cnt; ++j) cmax = fmaxf(cmax, s_l[j * HG_ + hh]);
    float nm = fmaxf(runmax, cmax);
    if (nm > runmax) {
      float rr = expf(runmax - nm);
      denom *= rr; accum *= rr; runmax = nm;
    }
    for (int j = 0; j < cnt; ++j) {
      float p = expf(s_l[j * HG_ + hh] - runmax);
      int srcn = s_src[j];
      int eap = s_ea[j];
      float ee = bf2f(tab[(size_t)(eap & 0xff) * DIM + d])
               + bf2f(tab[(size_t)(8 + ((eap >> 8) & 0xff)) * DIM + d])
               + bf2f(tab[(size_t)(16 + (eap >> 16)) * DIM + d]);
      float ve = bf2f(v[(size_t)srcn * DIM + d]) + ee;
      denom += p;
      accum += p * ve;
    }
  }
  size_t o = (size_t)n * DIM + d;
  hnew[o] = f2bf(accum / (denom + 1e-16f) + skip[o]);
}

// ---------------------------------------------------------------- LayerNorm: f32 in + bf16 resid -> bf16 out
__global__ __launch_bounds__(256) void ln_kernel(
    const float* __restrict__ in, const u16* __restrict__ resid,
    const float* __restrict__ g, const float* __restrict__ b,
    u16* __restrict__ outb, int relu) {
  int row = blockIdx.x * 4 + (threadIdx.x >> 6);
  int lane = threadIdx.x & 63;
  size_t base = (size_t)row * DIM + lane * 8;
  float x[8];
  {
    float4 v0 = *(const float4*)&in[base];
    float4 v1 = *(const float4*)&in[base + 4];
    x[0] = v0.x; x[1] = v0.y; x[2] = v0.z; x[3] = v0.w;
    x[4] = v1.x; x[5] = v1.y; x[6] = v1.z; x[7] = v1.w;
  }
  if (resid) {
    u16x8 rv = *(const u16x8*)&resid[base];
#pragma unroll
    for (int i = 0; i < 8; ++i) x[i] += bf2f(rv[i]);
  }
  float s = 0.f;
#pragma unroll
  for (int i = 0; i < 8; ++i) s += x[i];
#pragma unroll
  for (int off = 32; off; off >>= 1) s += __shfl_xor(s, off);
  float mu = s * (1.0f / DIM);
  float vs = 0.f;
#pragma unroll
  for (int i = 0; i < 8; ++i) { float t = x[i] - mu; vs += t * t; }
#pragma unroll
  for (int off = 32; off; off >>= 1) vs += __shfl_xor(vs, off);
  float rstd = 1.0f / sqrtf(vs * (1.0f / DIM) + 1e-5f);
  float4 g0 = *(const float4*)&g[lane * 8];
  float4 g1 = *(const float4*)&g[lane * 8 + 4];
  float4 b0 = *(const float4*)&b[lane * 8];
  float4 b1 = *(const float4*)&b[lane * 8 + 4];
  float gg[8] = {g0.x, g0.y, g0.z, g0.w, g1.x, g1.y, g1.z, g1.w};
  float bb[8] = {b0.x, b0.y, b0.z, b0.w, b1.x, b1.y, b1.z, b1.w};
  u16x8 ob;
#pragma unroll
  for (int i = 0; i < 8; ++i) {
    float y = (x[i] - mu) * rstd * gg[i] + bb[i];
    if (relu) y = fmaxf(y, 0.f);
    ob[i] = f2bf(y);
  }
  *(u16x8*)&outb[base] = ob;
}

// ---------------------------------------------------------------- readout (bf16 in)
__global__ __launch_bounds__(512) void pool_kernel(const u16* __restrict__ xg, float* __restrict__ pooled) {
  int g = blockIdx.x;
  int d = threadIdx.x;
  float acc = 0.f;
  for (int p = 0; p < NPG_; ++p) acc += bf2f(xg[((size_t)g * NPG_ + p) * DIM + d]);
  pooled[(size_t)g * DIM + d] = acc * (1.0f / NPG_);
}

// ================================================================ launch
extern "C" void kernel_launch(void* const* d_in, const int* in_sizes, int n_in,
                              void* d_out, int out_size, void* d_ws, size_t ws_size,
                              hipStream_t stream) {
  const float* atom_emb = (const float*)d_in[0];
  const float* bond_emb = (const float*)d_in[1];
  const float* gq_w = (const float*)d_in[2];
  const float* gk_w = (const float*)d_in[3];
  const float* gv_w = (const float*)d_in[4];
  const float* ge_w = (const float*)d_in[5];
  const float* gskip_w = (const float*)d_in[6];
  const float* mid_w = (const float*)d_in[7];
  const float* gq_b = (const float*)d_in[8];
  const float* gk_b = (const float*)d_in[9];
  const float* gv_b = (const float*)d_in[10];
  const float* gskip_b = (const float*)d_in[11];
  const float* mid_b = (const float*)d_in[12];
  const float* mid_g = (const float*)d_in[13];
  const float* mid_bt = (const float*)d_in[14];
  const float* tq_w = (const float*)d_in[15];
  const float* tk_w = (const float*)d_in[16];
  const float* tv_w = (const float*)d_in[17];
  const float* to_w = (const float*)d_in[18];
  const float* tq_b = (const float*)d_in[19];
  const float* tk_b = (const float*)d_in[20];
  const float* tv_b = (const float*)d_in[21];
  const float* to_b = (const float*)d_in[22];
  const float* ln1_g = (const float*)d_in[23];
  const float* ln1_b = (const float*)d_in[24];
  const float* f1_w = (const float*)d_in[25];
  const float* f1_b = (const float*)d_in[26];
  const float* f2_w = (const float*)d_in[27];
  const float* f2_b = (const float*)d_in[28];
  const float* ln2_g = (const float*)d_in[29];
  const float* ln2_b = (const float*)d_in[30];
  const float* out_w = (const float*)d_in[31];
  const float* out_b = (const float*)d_in[32];
  const int* x = (const int*)d_in[33];
  const int* ea = (const int*)d_in[34];
  const int* ei = (const int*)d_in[35];

  // ---- workspace map (~245 MiB total; aliased by liveness)
  char* wbase = (char*)d_ws;
  size_t woff = 0;
  auto ALLOC = [&](size_t bytes) -> void* {
    void* r = wbase + woff;
    woff += (bytes + 255) & ~(size_t)255;
    return r;
  };
  const size_t ND = (size_t)N_NODES * DIM * sizeof(float);    // 64 MiB
  const size_t NDH = (size_t)N_NODES * DIM * sizeof(u16);     // 32 MiB
  u16*   wt     = (u16*)ALLOC((size_t)17825792 * sizeof(u16));  // 34 MiB weights bf16
  u16*   hb     = (u16*)ALLOC(NDH);   // residual h (bf16)
  u16*   Abuf   = (u16*)ALLOC(NDH);   // gconv q / agg-out / tlayer q / attn-O / FF chunk
  u16*   Bbuf   = (u16*)ALLOC(NDH);   // k
  u16*   Cbuf   = (u16*)ALLOC(NDH);   // gconv v / tlayer V^T
  float* E      = (float*)ALLOC(ND);  // gconv skip f32 -> pre-LN tmp f32
  u16*   U      = (u16*)ALLOC((size_t)16777216);  // logits f32 (16MiB) | S/P bf16 per 128-z round
  u16*   tab    = (u16*)ALLOC(24 * DIM * sizeof(u16));
  float* pooled = (float*)ALLOC((size_t)NG * DIM * sizeof(float));
  int* deg      = (int*)ALLOC(N_NODES * sizeof(int));
  int* cur      = (int*)ALLOC(N_NODES * sizeof(int));
  int* rp       = (int*)ALLOC((N_NODES + 1) * sizeof(int));
  int* csr      = (int*)ALLOC((size_t)NE * sizeof(int));
  (void)ws_size; (void)in_sizes; (void)n_in; (void)out_size;

  const size_t DD = (size_t)DIM * DIM;
  const size_t DD4 = 4 * DD;
  u16* gqT = wt;            u16* gkT = wt + DD4;      u16* gvT = wt + 2 * DD4;
  u16* gskipT = wt + 3*DD4; u16* midT = wt + 4 * DD4;
  u16* tqT = wt + 5 * DD4;  u16* tkT = wt + 6 * DD4;  u16* tvT = wt + 7 * DD4;
  u16* toT = wt + 8 * DD4;
  u16* f1T = wt + 9 * DD4;
  u16* f2T = f1T + (size_t)4 * DIM * FF_;

  auto wcvt = [&](const float* W, u16* Wt, int K, int N, int L2) {
    dim3 grid(N / 32, K / 32, L2);
    wcvt_kernel<<<grid, 256, 0, stream>>>(W, Wt, K, N);
  };
  auto mgemm = [&](const u16* A_, const u16* Bt_, const float* bias_,
                   float* Cf_, u16* Cb_, int M_, int K_, int Nout_,
                   int relu_, int bf16o_, int vtout_) {
    dim3 grid(Nout_ / 128, M_ / 128);
    gemm_mfma_kernel<<<grid, 256, 0, stream>>>(A_, Bt_, bias_, Cf_, Cb_, K_, Nout_, relu_, bf16o_, vtout_);
  };

  // ---- weight convert/transpose
  wcvt(gq_w, gqT, DIM, DIM, 4);   wcvt(gk_w, gkT, DIM, DIM, 4);
  wcvt(gv_w, gvT, DIM, DIM, 4);   wcvt(gskip_w, gskipT, DIM, DIM, 4);
  wcvt(mid_w, midT, DIM, DIM, 4);
  wcvt(tq_w, tqT, DIM, DIM, 4);   wcvt(tk_w, tkT, DIM, DIM, 4);
  wcvt(tv_w, tvT, DIM, DIM, 4);   wcvt(to_w, toT, DIM, DIM, 4);
  wcvt(f1_w, f1T, DIM, FF_, 4);   wcvt(f2_w, f2T, FF_, DIM, 4);

  // ---- CSR build
  hipMemsetAsync(deg, 0, N_NODES * sizeof(int), stream);
  hipMemsetAsync(cur, 0, N_NODES * sizeof(int), stream);
  deg_count_kernel<<<NE / 256, 256, 0, stream>>>(ei, deg);
  scan_kernel<<<1, 1024, 0, stream>>>(deg, rp);
  scatter_kernel<<<NE / 256, 256, 0, stream>>>(ei, rp, cur, csr);

  // ---- encoder
  atom_enc_kernel<<<N_NODES, 128, 0, stream>>>(atom_emb, x, hb);

  // ---- graph-conv layers
  for (int i = 0; i < NL; ++i) {
    bemb_proj_kernel<<<24, 512, 0, stream>>>(bond_emb, ge_w + i * DD, tab);
    mgemm(hb, gqT + i * DD, gq_b + i * DIM, nullptr, Abuf, N_NODES, DIM, DIM, 0, 1, 0);   // q bf16
    mgemm(hb, gkT + i * DD, gk_b + i * DIM, nullptr, Bbuf, N_NODES, DIM, DIM, 0, 1, 0);   // k bf16
    mgemm(hb, gvT + i * DD, gv_b + i * DIM, nullptr, Cbuf, N_NODES, DIM, DIM, 0, 1, 0);   // v bf16
    mgemm(hb, gskipT + i * DD, gskip_b + i * DIM, E, nullptr, N_NODES, DIM, DIM, 0, 0, 0); // skip f32
    edge_logits_kernel<<<NE / 4, 256, 0, stream>>>(Abuf, Bbuf, tab, ei, ea, (float*)U);
    edge_agg_kernel<<<N_NODES, 512, 0, stream>>>(Cbuf, tab, (float*)U, E, ei, ea, rp, csr, Abuf);
    mgemm(Abuf, midT + i * DD, mid_b + i * DIM, E, nullptr, N_NODES, DIM, DIM, 0, 0, 0);
    ln_kernel<<<N_NODES / 4, 256, 0, stream>>>(E, nullptr, mid_g + i * DIM, mid_bt + i * DIM, hb, 1);
  }

  // ---- transformer layers
  for (int i = 0; i < NL; ++i) {
    mgemm(hb, tqT + i * DD, tq_b + i * DIM, nullptr, Abuf, N_NODES, DIM, DIM, 0, 1, 0);   // q bf16
    mgemm(hb, tkT + i * DD, tk_b + i * DIM, nullptr, Bbuf, N_NODES, DIM, DIM, 0, 1, 0);   // k bf16
    mgemm(hb, tvT + i * DD, tv_b + i * DIM, nullptr, Cbuf, N_NODES, DIM, DIM, 0, 1, 1);   // V^T bf16
    for (int rnd = 0; rnd < 4; ++rnd) {   // 128 (g,h)-slices per round; S/P in 16MiB U
      attn_s_mfma_kernel<<<dim3(2, 2, 128), 256, 0, stream>>>(Abuf, Bbuf, U, rnd * 128);
      softmax256_kernel<<<(128 * NPG_) / 4, 256, 0, stream>>>(U);
      attn_o_mfma_kernel<<<dim3(1, 2, 128), 256, 0, stream>>>(U, Cbuf, Abuf, rnd * 128);
    }
    mgemm(Abuf, toT + i * DD, to_b + i * DIM, E, nullptr, N_NODES, DIM, DIM, 0, 0, 0);
    ln_kernel<<<N_NODES / 4, 256, 0, stream>>>(E, hb, ln1_g + i * DIM, ln1_b + i * DIM, hb, 0);
    for (int c = 0; c < 4; ++c) {         // FF in 4 row-chunks of 8192 through Abuf
      mgemm(hb + (size_t)c * 8192 * DIM, f1T + (size_t)i * DIM * FF_, f1_b + i * FF_,
            nullptr, Abuf, 8192, DIM, FF_, 1, 1, 0);
      mgemm(Abuf, f2T + (size_t)i * FF_ * DIM, f2_b + i * DIM,
            E + (size_t)c * 8192 * DIM, nullptr, 8192, FF_, DIM, 0, 0, 0);
    }
    ln_kernel<<<N_NODES / 4, 256, 0, stream>>>(E, hb, ln2_g + i * DIM, ln2_b + i * DIM, hb, 0);
  }

  // ---- readout
  pool_kernel<<<NG, 512, 0, stream>>>(hb, pooled);
  gemm_bias_kernel<<<dim3(OUTD / 64, NG / 64), 256, 0, stream>>>(pooled, out_w, out_b, (float*)d_out, NG, DIM, OUTD, 0);
}

// Round 8
// 5624.430 us; speedup vs baseline: 1.0622x; 1.0622x over previous
//
#include <hip/hip_runtime.h>
#include <hip/hip_bf16.h>
#include <math.h>

#define N_NODES 32768
#define DIM     512
#define NE      524288
#define NL      4
#define NG      128
#define NPG_    256
#define HG_     8
#define CG_     64
#define HT_     4
#define CT_     128
#define FF_     2048
#define AF_     9
#define AV_     64
#define BV_     8
#define OUTD    128

typedef unsigned short u16;
typedef __attribute__((ext_vector_type(8))) short bhalf8;
typedef __attribute__((ext_vector_type(4))) float floatx4;
typedef __attribute__((ext_vector_type(8))) unsigned short u16x8;
typedef __attribute__((ext_vector_type(4))) unsigned short u16x4;

__device__ __forceinline__ u16 f2bf(float f) {
  union { float f; unsigned u; } x; x.f = f;
  unsigned r = x.u + 0x7fffu + ((x.u >> 16) & 1u);   // round-nearest-even
  return (u16)(r >> 16);
}
__device__ __forceinline__ float bf2f(u16 u) {
  union { unsigned u; float f; } x; x.u = ((unsigned)u) << 16; return x.f;
}

#define GL2LDS(gp, lp) __builtin_amdgcn_global_load_lds( \
    (const __attribute__((address_space(1))) unsigned int*)(gp), \
    (__attribute__((address_space(3))) unsigned int*)(lp), 16, 0, 0)

// ---------------------------------------------------------------- encoder (bf16 out)
__global__ __launch_bounds__(128) void atom_enc_kernel(
    const float* __restrict__ emb, const int* __restrict__ x, u16* __restrict__ hb) {
  int n = blockIdx.x;
  int d4 = threadIdx.x;
  const int* xr = x + n * AF_;
  float4 acc = {0.f, 0.f, 0.f, 0.f};
#pragma unroll
  for (int f = 0; f < AF_; ++f) {
    int idx = xr[f];
    const float4 v = *(const float4*)&emb[((size_t)(f * AV_ + idx)) * DIM + 4 * d4];
    acc.x += v.x; acc.y += v.y; acc.z += v.z; acc.w += v.w;
  }
  u16x4 o;
  o[0] = f2bf(acc.x); o[1] = f2bf(acc.y); o[2] = f2bf(acc.z); o[3] = f2bf(acc.w);
  *(u16x4*)&hb[(size_t)n * DIM + 4 * d4] = o;
}

// tab[r, d] = bf16( bond_emb[r, :] @ ge_w[:, d] )
// grid(24, 8): block (r, c8) -> 64 cols, 512 thr = 64 cols x 8 k-parts, LDS reduce
__global__ __launch_bounds__(512) void bemb_proj_kernel(
    const float* __restrict__ bond_emb, const float* __restrict__ gew, u16* __restrict__ tab) {
  __shared__ float red[8][64];
  int r = blockIdx.x;
  int col = (threadIdx.x & 63) + blockIdx.y * 64;
  int kp = threadIdx.x >> 6;
  const float* a = bond_emb + (size_t)r * DIM + kp * 64;
  const float* w = gew + (size_t)kp * 64 * DIM + col;
  float acc = 0.f;
#pragma unroll 8
  for (int kx = 0; kx < 64; ++kx)
    acc += a[kx] * w[(size_t)kx * DIM];
  red[kp][threadIdx.x & 63] = acc;
  __syncthreads();
  if (threadIdx.x < 64) {
    float s = 0.f;
#pragma unroll
    for (int p = 0; p < 8; ++p) s += red[p][threadIdx.x];
    tab[(size_t)r * DIM + col] = f2bf(s);
  }
}

// ---------------------------------------------------------------- weight cvt+transpose
// W [z][K][N] f32 -> Wt [z][N][K] bf16
__global__ __launch_bounds__(256) void wcvt_kernel(
    const float* __restrict__ W, u16* __restrict__ Wt, int K, int N) {
  __shared__ float t[32][33];
  const size_t mo = (size_t)blockIdx.z * K * N;
  int k0 = blockIdx.y * 32, n0 = blockIdx.x * 32;
  int tx = threadIdx.x & 31, ty = threadIdx.x >> 5;
#pragma unroll
  for (int i = 0; i < 32; i += 8)
    t[ty + i][tx] = W[mo + (size_t)(k0 + ty + i) * N + n0 + tx];
  __syncthreads();
#pragma unroll
  for (int i = 0; i < 32; i += 8)
    Wt[mo + (size_t)(n0 + ty + i) * K + k0 + tx] = f2bf(t[tx][ty + i]);
}

// ---------------------------------------------------------------- MFMA GEMM
// C[M,Nout] = A[M,K](bf16) @ Bt[Nout,K](bf16)^T + bias; 128x128 tile, BK=32,
// 4 waves (2x2), each wave 64x64 via 4x4 frags of 16x16x32.
// vtout: write bf16 transposed per-graph: vt[(row>>8)*512 + col][row&255]
__global__ __launch_bounds__(256) void gemm_mfma_kernel(
    const u16* __restrict__ A, const u16* __restrict__ Bt,
    const float* __restrict__ bias, float* __restrict__ Cf, u16* __restrict__ Cb,
    int K, int Nout, int relu, int bf16out, int vtout) {
  __shared__ __align__(16) u16 As[4096];   // [128 rows][32 k]
  __shared__ __align__(16) u16 Bs[4096];
  const int tid = threadIdx.x;
  const int wave = tid >> 6, lane = tid & 63;
  const int bm = blockIdx.y * 128, bn = blockIdx.x * 128;
  const int wr = wave >> 1, wc = wave & 1;

  const size_t rowA = (size_t)bm + (tid >> 2);
  const size_t rowB = (size_t)bn + (tid >> 2);
  const int gofs = (tid & 3) * 8;
  const u16* pA = A + rowA * K + gofs;
  const u16* pB = Bt + rowB * K + gofs;
  u16* lA0 = &As[wave * 512];
  u16* lB0 = &Bs[wave * 512];
  const size_t skip64 = (size_t)64 * K;

  floatx4 acc[4][4] = {};
  const int r = lane & 15, kg = lane >> 4;
  const int aoff = (wr * 64 + r) * 32 + kg * 8;
  const int boff = (wc * 64 + r) * 32 + kg * 8;

  for (int k0 = 0; k0 < K; k0 += 32) {
    GL2LDS(pA + k0, lA0);
    GL2LDS(pA + skip64 + k0, lA0 + 2048);
    GL2LDS(pB + k0, lB0);
    GL2LDS(pB + skip64 + k0, lB0 + 2048);
    __syncthreads();
    bhalf8 af[4], bg[4];
#pragma unroll
    for (int mi = 0; mi < 4; ++mi) af[mi] = *(const bhalf8*)&As[aoff + mi * 512];
#pragma unroll
    for (int ni = 0; ni < 4; ++ni) bg[ni] = *(const bhalf8*)&Bs[boff + ni * 512];
#pragma unroll
    for (int mi = 0; mi < 4; ++mi)
#pragma unroll
      for (int ni = 0; ni < 4; ++ni)
        acc[mi][ni] = __builtin_amdgcn_mfma_f32_16x16x32_bf16(af[mi], bg[ni], acc[mi][ni], 0, 0, 0);
    __syncthreads();
  }

  // C/D layout: col = lane&15, row = (lane>>4)*4 + reg
  const int rb = (lane >> 4) * 4;
  const int cc = lane & 15;
#pragma unroll
  for (int mi = 0; mi < 4; ++mi) {
#pragma unroll
    for (int ni = 0; ni < 4; ++ni) {
      int gr0 = bm + wr * 64 + mi * 16 + rb;
      int gc = bn + wc * 64 + ni * 16 + cc;
      float bv = bias[gc];
#pragma unroll
      for (int reg = 0; reg < 4; ++reg) {
        int gr = gr0 + reg;
        float v = acc[mi][ni][reg] + bv;
        if (relu) v = fmaxf(v, 0.f);
        if (vtout)        Cb[((size_t)(gr >> 8) * DIM + gc) * NPG_ + (gr & 255)] = f2bf(v);
        else if (bf16out) Cb[(size_t)gr * Nout + gc] = f2bf(v);
        else              Cf[(size_t)gr * Nout + gc] = v;
      }
    }
  }
}

// ---------------------------------------------------------------- MFMA attention S = bf16(QK^T/sqrt(128))
__global__ __launch_bounds__(256) void attn_s_mfma_kernel(
    const u16* __restrict__ q, const u16* __restrict__ k, u16* __restrict__ S, int zbase) {
  __shared__ __align__(16) u16 As[4096];
  __shared__ __align__(16) u16 Bs[4096];
  const int tid = threadIdx.x;
  const int wave = tid >> 6, lane = tid & 63;
  const int zl = blockIdx.z, z = zbase + zl, g = z >> 2, hh = z & 3;
  const int bm = blockIdx.y * 128, bn = blockIdx.x * 128;
  const int wr = wave >> 1, wc = wave & 1;
  const u16* qg = q + (size_t)g * NPG_ * DIM + hh * CT_;
  const u16* kg2 = k + (size_t)g * NPG_ * DIM + hh * CT_;
  const u16* pA = qg + (size_t)(bm + (tid >> 2)) * DIM + (tid & 3) * 8;
  const u16* pB = kg2 + (size_t)(bn + (tid >> 2)) * DIM + (tid & 3) * 8;
  u16* lA0 = &As[wave * 512];
  u16* lB0 = &Bs[wave * 512];
  const size_t skip64 = (size_t)64 * DIM;
  floatx4 acc[4][4] = {};
  const int r = lane & 15, kg_ = lane >> 4;
  const int aoff = (wr * 64 + r) * 32 + kg_ * 8;
  const int boff = (wc * 64 + r) * 32 + kg_ * 8;
  for (int k0 = 0; k0 < CT_; k0 += 32) {
    GL2LDS(pA + k0, lA0);
    GL2LDS(pA + skip64 + k0, lA0 + 2048);
    GL2LDS(pB + k0, lB0);
    GL2LDS(pB + skip64 + k0, lB0 + 2048);
    __syncthreads();
    bhalf8 af[4], bg[4];
#pragma unroll
    for (int mi = 0; mi < 4; ++mi) af[mi] = *(const bhalf8*)&As[aoff + mi * 512];
#pragma unroll
    for (int ni = 0; ni < 4; ++ni) bg[ni] = *(const bhalf8*)&Bs[boff + ni * 512];
#pragma unroll
    for (int mi = 0; mi < 4; ++mi)
#pragma unroll
      for (int ni = 0; ni < 4; ++ni)
        acc[mi][ni] = __builtin_amdgcn_mfma_f32_16x16x32_bf16(af[mi], bg[ni], acc[mi][ni], 0, 0, 0);
    __syncthreads();
  }
  const float sc = 0.08838834764831845f;   // 1/sqrt(128)
  u16* C = S + (size_t)zl * NPG_ * NPG_;
  const int rb = (lane >> 4) * 4, cc = lane & 15;
#pragma unroll
  for (int mi = 0; mi < 4; ++mi)
#pragma unroll
    for (int ni = 0; ni < 4; ++ni) {
      int gr = bm + wr * 64 + mi * 16 + rb;
      int gc = bn + wc * 64 + ni * 16 + cc;
#pragma unroll
      for (int reg = 0; reg < 4; ++reg)
        C[(size_t)(gr + reg) * NPG_ + gc] = f2bf(acc[mi][ni][reg] * sc);
    }
}

// in-place softmax on bf16 rows (256 wide)
__global__ __launch_bounds__(256) void softmax256_kernel(u16* __restrict__ SP) {
  size_t row = (size_t)blockIdx.x * 4 + (threadIdx.x >> 6);
  int lane = threadIdx.x & 63;
  u16* r = SP + row * NPG_;
  u16x4 v = *(u16x4*)&r[lane * 4];
  float x0 = bf2f(v[0]), x1 = bf2f(v[1]), x2 = bf2f(v[2]), x3 = bf2f(v[3]);
  float m = fmaxf(fmaxf(x0, x1), fmaxf(x2, x3));
#pragma unroll
  for (int off = 32; off; off >>= 1) m = fmaxf(m, __shfl_xor(m, off));
  x0 = expf(x0 - m); x1 = expf(x1 - m); x2 = expf(x2 - m); x3 = expf(x3 - m);
  float s = x0 + x1 + x2 + x3;
#pragma unroll
  for (int off = 32; off; off >>= 1) s += __shfl_xor(s, off);
  float inv = 1.0f / s;
  u16x4 o;
  o[0] = f2bf(x0 * inv); o[1] = f2bf(x1 * inv);
  o[2] = f2bf(x2 * inv); o[3] = f2bf(x3 * inv);
  *(u16x4*)&r[lane * 4] = o;
}

// O[g,qi,h*128+c] = sum_ki P[zl,qi,ki] * vt[g, h*128+c, ki]
__global__ __launch_bounds__(256) void attn_o_mfma_kernel(
    const u16* __restrict__ P, const u16* __restrict__ vt, u16* __restrict__ O, int zbase) {
  __shared__ __align__(16) u16 As[4096];
  __shared__ __align__(16) u16 Bs[4096];
  const int tid = threadIdx.x;
  const int wave = tid >> 6, lane = tid & 63;
  const int zl = blockIdx.z, z = zbase + zl, g = z >> 2, hh = z & 3;
  const int bm = blockIdx.y * 128;
  const int wr = wave >> 1, wc = wave & 1;
  const u16* A = P + (size_t)zl * NPG_ * NPG_;
  const u16* Bt = vt + ((size_t)g * DIM + hh * CT_) * NPG_;
  const u16* pA = A + (size_t)(bm + (tid >> 2)) * NPG_ + (tid & 3) * 8;
  const u16* pB = Bt + (size_t)(tid >> 2) * NPG_ + (tid & 3) * 8;
  u16* lA0 = &As[wave * 512];
  u16* lB0 = &Bs[wave * 512];
  const size_t skip64 = (size_t)64 * NPG_;
  floatx4 acc[4][4] = {};
  const int r = lane & 15, kg_ = lane >> 4;
  const int aoff = (wr * 64 + r) * 32 + kg_ * 8;
  const int boff = (wc * 64 + r) * 32 + kg_ * 8;
  for (int k0 = 0; k0 < NPG_; k0 += 32) {
    GL2LDS(pA + k0, lA0);
    GL2LDS(pA + skip64 + k0, lA0 + 2048);
    GL2LDS(pB + k0, lB0);
    GL2LDS(pB + skip64 + k0, lB0 + 2048);
    __syncthreads();
    bhalf8 af[4], bg[4];
#pragma unroll
    for (int mi = 0; mi < 4; ++mi) af[mi] = *(const bhalf8*)&As[aoff + mi * 512];
#pragma unroll
    for (int ni = 0; ni < 4; ++ni) bg[ni] = *(const bhalf8*)&Bs[boff + ni * 512];
#pragma unroll
    for (int mi = 0; mi < 4; ++mi)
#pragma unroll
      for (int ni = 0; ni < 4; ++ni)
        acc[mi][ni] = __builtin_amdgcn_mfma_f32_16x16x32_bf16(af[mi], bg[ni], acc[mi][ni], 0, 0, 0);
    __syncthreads();
  }
  u16* C = O + ((size_t)g * NPG_) * DIM + hh * CT_;
  const int rb = (lane >> 4) * 4, cc = lane & 15;
#pragma unroll
  for (int mi = 0; mi < 4; ++mi)
#pragma unroll
    for (int ni = 0; ni < 4; ++ni) {
      int gr = bm + wr * 64 + mi * 16 + rb;
      int gc = wc * 64 + ni * 16 + cc;
#pragma unroll
      for (int reg = 0; reg < 4; ++reg)
        C[(size_t)(gr + reg) * DIM + gc] = f2bf(acc[mi][ni][reg]);
    }
}

// ---------------------------------------------------------------- f32 GEMM (final head)
__global__ __launch_bounds__(256) void gemm_bias_kernel(
    const float* __restrict__ A, const float* __restrict__ W,
    const float* __restrict__ bias, float* __restrict__ C,
    int M, int K, int Nout, int relu) {
  __shared__ float As[16][65];
  __shared__ float Bs[16][64];
  const int bm = blockIdx.y * 64;
  const int bn = blockIdx.x * 64;
  const int tid = threadIdx.x;
  const int tx = tid & 15, ty = tid >> 4;
  float acc[4][4] = {};
  for (int k0 = 0; k0 < K; k0 += 16) {
    {
      int row = tid >> 2;
      int kq = (tid & 3) << 2;
      float4 a = *(const float4*)&A[(size_t)(bm + row) * K + k0 + kq];
      As[kq + 0][row] = a.x; As[kq + 1][row] = a.y; As[kq + 2][row] = a.z; As[kq + 3][row] = a.w;
    }
    {
      int krow = tid >> 4;
      int cq = (tid & 15) << 2;
      *(float4*)&Bs[krow][cq] = *(const float4*)&W[(size_t)(k0 + krow) * Nout + bn + cq];
    }
    __syncthreads();
#pragma unroll
    for (int kk = 0; kk < 16; ++kk) {
      float a[4];
#pragma unroll
      for (int i = 0; i < 4; ++i) a[i] = As[kk][ty * 4 + i];
      float4 b4 = *(const float4*)&Bs[kk][tx * 4];
      float b[4] = {b4.x, b4.y, b4.z, b4.w};
#pragma unroll
      for (int i = 0; i < 4; ++i)
#pragma unroll
        for (int j = 0; j < 4; ++j) acc[i][j] = fmaf(a[i], b[j], acc[i][j]);
    }
    __syncthreads();
  }
  float4 bv = *(const float4*)&bias[bn + tx * 4];
#pragma unroll
  for (int i = 0; i < 4; ++i) {
    int row = bm + ty * 4 + i;
    float4 o;
    o.x = acc[i][0] + bv.x; o.y = acc[i][1] + bv.y;
    o.z = acc[i][2] + bv.z; o.w = acc[i][3] + bv.w;
    if (relu) {
      o.x = fmaxf(o.x, 0.f); o.y = fmaxf(o.y, 0.f);
      o.z = fmaxf(o.z, 0.f); o.w = fmaxf(o.w, 0.f);
    }
    *(float4*)&C[(size_t)row * Nout + bn + tx * 4] = o;
  }
}

// ---------------------------------------------------------------- CSR build
__global__ __launch_bounds__(256) void deg_count_kernel(const int* __restrict__ ei, int* __restrict__ deg) {
  int e = blockIdx.x * 256 + threadIdx.x;
  atomicAdd(&deg[ei[NE + e]], 1);
}

__global__ __launch_bounds__(1024) void scan_kernel(const int* __restrict__ deg, int* __restrict__ rp) {
  __shared__ int sums[1024];
  int t = threadIdx.x;
  int base = t * 32;
  int local[32];
  int s = 0;
#pragma unroll
  for (int i = 0; i < 32; ++i) { local[i] = s; s += deg[base + i]; }
  sums[t] = s;
  __syncthreads();
  for (int off = 1; off < 1024; off <<= 1) {
    int other = (t >= off) ? sums[t - off] : 0;
    __syncthreads();
    sums[t] += other;
    __syncthreads();
  }
  int chunk_off = sums[t] - s;
#pragma unroll
  for (int i = 0; i < 32; ++i) rp[base + i] = chunk_off + local[i];
  if (t == 1023) rp[N_NODES] = sums[1023];
}

__global__ __launch_bounds__(256) void scatter_kernel(
    const int* __restrict__ ei, const int* __restrict__ rp,
    int* __restrict__ cur, int* __restrict__ csr) {
  int e = blockIdx.x * 256 + threadIdx.x;
  int d = ei[NE + e];
  int pos = atomicAdd(&cur[d], 1);
  csr[rp[d] + pos] = e;
}

// ---------------------------------------------------------------- edge logits (bf16 q/k/tab)
__global__ __launch_bounds__(256) void edge_logits_kernel(
    const u16* __restrict__ q, const u16* __restrict__ k, const u16* __restrict__ tab,
    const int* __restrict__ ei, const int* __restrict__ ea, float* __restrict__ logits) {
  int e = blockIdx.x * 4 + (threadIdx.x >> 6);
  int lane = threadIdx.x & 63;
  int src = ei[e], dst = ei[NE + e];
  int a0 = ea[e * 3], a1 = ea[e * 3 + 1], a2 = ea[e * 3 + 2];
  const u16x8 qv = *(const u16x8*)&q[(size_t)dst * DIM + lane * 8];
  const u16x8 kv = *(const u16x8*)&k[(size_t)src * DIM + lane * 8];
  const size_t to = (size_t)lane * 8;
  const u16x8 e0 = *(const u16x8*)&tab[(size_t)a0 * DIM + to];
  const u16x8 e1 = *(const u16x8*)&tab[(size_t)(8 + a1) * DIM + to];
  const u16x8 e2 = *(const u16x8*)&tab[(size_t)(16 + a2) * DIM + to];
  float acc = 0.f;
#pragma unroll
  for (int j = 0; j < 8; ++j) {
    float ee = bf2f(e0[j]) + bf2f(e1[j]) + bf2f(e2[j]);
    acc += bf2f(qv[j]) * (bf2f(kv[j]) + ee);
  }
  acc += __shfl_xor(acc, 1);
  acc += __shfl_xor(acc, 2);
  acc += __shfl_xor(acc, 4);
  if ((lane & 7) == 0) logits[(size_t)e * HG_ + (lane >> 3)] = acc * 0.125f;
}

// ---------------------------------------------------------------- edge aggregation (per node)
// Restructured: exp once per (edge,head); denom per-thread; tab-term via 24x8 weight
// table (algebraic identity: sum_j p_j*ee_j = sum_r w_r*tab_r), applied once per node.
#define CHUNK 128
__global__ __launch_bounds__(512) void edge_agg_kernel(
    const u16* __restrict__ v, const u16* __restrict__ tab, const float* __restrict__ logits,
    const float* __restrict__ skip, const int* __restrict__ ei, const int* __restrict__ ea,
    const int* __restrict__ rp, const int* __restrict__ csr, u16* __restrict__ hnew) {
  int n = blockIdx.x;
  int d = threadIdx.x;
  int hh = d >> 6;
  int lane = d & 63;
  int start = rp[n];
  int deg = rp[n + 1] - start;
  __shared__ int s_eid[CHUNK];
  __shared__ int s_src[CHUNK];
  __shared__ int s_ea[CHUNK];
  __shared__ float s_p[CHUNK * HG_];
  __shared__ float s_w[24 * HG_];
  __shared__ float s_max[HG_];
  __shared__ float s_resc[HG_];
  if (d < 24 * HG_) s_w[d] = 0.f;
  if (d < HG_) s_max[d] = -3.0e38f;
  float accum = 0.f, den = 0.f;
  for (int c0 = 0; c0 < deg; c0 += CHUNK) {
    int cnt = min(CHUNK, deg - c0);
    __syncthreads();                       // also covers s_w/s_max init on first iter
    if (d < cnt) {
      int eid = csr[start + c0 + d];
      s_eid[d] = eid;
      s_src[d] = ei[eid];
      s_ea[d] = ea[eid * 3] | (ea[eid * 3 + 1] << 8) | (ea[eid * 3 + 2] << 16);
    }
    __syncthreads();
    for (int jh = d; jh < cnt * HG_; jh += 512)
      s_p[jh] = logits[(size_t)s_eid[jh >> 3] * HG_ + (jh & 7)];
    __syncthreads();
    // chunk max per head: wave hh reduces over j
    float cm = -3.0e38f;
    for (int j = lane; j < cnt; j += 64)
      cm = fmaxf(cm, s_p[j * HG_ + hh]);
#pragma unroll
    for (int off = 32; off; off >>= 1) cm = fmaxf(cm, __shfl_xor(cm, off));
    if (lane == 0) {
      float om = s_max[hh];
      float nm = fmaxf(om, cm);
      s_resc[hh] = (nm > om) ? expf(om - nm) : 1.0f;
      s_max[hh] = nm;
    }
    __syncthreads();
    // apply rescale to running state
    float rsc = s_resc[hh];
    accum *= rsc;
    den *= rsc;
    if (d < 24 * HG_) s_w[d] *= s_resc[d & 7];
    __syncthreads();
    // exp once per (edge,head) + accumulate tab-row weights
    for (int jh = d; jh < cnt * HG_; jh += 512) {
      int h2 = jh & 7;
      float p = expf(s_p[jh] - s_max[h2]);
      s_p[jh] = p;
      int eap = s_ea[jh >> 3];
      atomicAdd(&s_w[(eap & 0xff) * HG_ + h2], p);
      atomicAdd(&s_w[(8 + ((eap >> 8) & 0xff)) * HG_ + h2], p);
      atomicAdd(&s_w[(16 + (eap >> 16)) * HG_ + h2], p);
    }
    __syncthreads();
    // per-dim accumulation: 1 LDS broadcast + 1 gather + fma per edge
    for (int j = 0; j < cnt; ++j) {
      float p = s_p[j * HG_ + hh];
      den += p;
      accum = fmaf(p, bf2f(v[(size_t)s_src[j] * DIM + d]), accum);
    }
  }
  __syncthreads();   // s_w final (also orders deg==0 init)
#pragma unroll
  for (int r2 = 0; r2 < 24; ++r2)
    accum = fmaf(s_w[r2 * HG_ + hh], bf2f(tab[(size_t)r2 * DIM + d]), accum);
  size_t o = (size_t)n * DIM + d;
  hnew[o] = f2bf(accum / (den + 1e-16f) + skip[o]);
}

// ---------------------------------------------------------------- LayerNorm: f32 in + bf16 resid -> bf16 out
__global__ __launch_bounds__(256) void ln_kernel(
    const float* __restrict__ in, const u16* __restrict__ resid,
    const float* __restrict__ g, const float* __restrict__ b,
    u16* __restrict__ outb, int relu) {
  int row = blockIdx.x * 4 + (threadIdx.x >> 6);
  int lane = threadIdx.x & 63;
  size_t base = (size_t)row * DIM + lane * 8;
  float x[8];
  {
    float4 v0 = *(const float4*)&in[base];
    float4 v1 = *(const float4*)&in[base + 4];
    x[0] = v0.x; x[1] = v0.y; x[2] = v0.z; x[3] = v0.w;
    x[4] = v1.x; x[5] = v1.y; x[6] = v1.z; x[7] = v1.w;
  }
  if (resid) {
    u16x8 rv = *(const u16x8*)&resid[base];
#pragma unroll
    for (int i = 0; i < 8; ++i) x[i] += bf2f(rv[i]);
  }
  float s = 0.f;
#pragma unroll
  for (int i = 0; i < 8; ++i) s += x[i];
#pragma unroll
  for (int off = 32; off; off >>= 1) s += __shfl_xor(s, off);
  float mu = s * (1.0f / DIM);
  float vs = 0.f;
#pragma unroll
  for (int i = 0; i < 8; ++i) { float t = x[i] - mu; vs += t * t; }
#pragma unroll
  for (int off = 32; off; off >>= 1) vs += __shfl_xor(vs, off);
  float rstd = 1.0f / sqrtf(vs * (1.0f / DIM) + 1e-5f);
  float4 g0 = *(const float4*)&g[lane * 8];
  float4 g1 = *(const float4*)&g[lane * 8 + 4];
  float4 b0 = *(const float4*)&b[lane * 8];
  float4 b1 = *(const float4*)&b[lane * 8 + 4];
  float gg[8] = {g0.x, g0.y, g0.z, g0.w, g1.x, g1.y, g1.z, g1.w};
  float bb[8] = {b0.x, b0.y, b0.z, b0.w, b1.x, b1.y, b1.z, b1.w};
  u16x8 ob;
#pragma unroll
  for (int i = 0; i < 8; ++i) {
    float y = (x[i] - mu) * rstd * gg[i] + bb[i];
    if (relu) y = fmaxf(y, 0.f);
    ob[i] = f2bf(y);
  }
  *(u16x8*)&outb[base] = ob;
}

// ---------------------------------------------------------------- readout (bf16 in)
__global__ __launch_bounds__(512) void pool_kernel(const u16* __restrict__ xg, float* __restrict__ pooled) {
  int g = blockIdx.x;
  int d = threadIdx.x;
  float acc = 0.f;
  for (int p = 0; p < NPG_; ++p) acc += bf2f(xg[((size_t)g * NPG_ + p) * DIM + d]);
  pooled[(size_t)g * DIM + d] = acc * (1.0f / NPG_);
}

// ================================================================ launch
extern "C" void kernel_launch(void* const* d_in, const int* in_sizes, int n_in,
                              void* d_out, int out_size, void* d_ws, size_t ws_size,
                              hipStream_t stream) {
  const float* atom_emb = (const float*)d_in[0];
  const float* bond_emb = (const float*)d_in[1];
  const float* gq_w = (const float*)d_in[2];
  const float* gk_w = (const float*)d_in[3];
  const float* gv_w = (const float*)d_in[4];
  const float* ge_w = (const float*)d_in[5];
  const float* gskip_w = (const float*)d_in[6];
  const float* mid_w = (const float*)d_in[7];
  const float* gq_b = (const float*)d_in[8];
  const float* gk_b = (const float*)d_in[9];
  const float* gv_b = (const float*)d_in[10];
  const float* gskip_b = (const float*)d_in[11];
  const float* mid_b = (const float*)d_in[12];
  const float* mid_g = (const float*)d_in[13];
  const float* mid_bt = (const float*)d_in[14];
  const float* tq_w = (const float*)d_in[15];
  const float* tk_w = (const float*)d_in[16];
  const float* tv_w = (const float*)d_in[17];
  const float* to_w = (const float*)d_in[18];
  const float* tq_b = (const float*)d_in[19];
  const float* tk_b = (const float*)d_in[20];
  const float* tv_b = (const float*)d_in[21];
  const float* to_b = (const float*)d_in[22];
  const float* ln1_g = (const float*)d_in[23];
  const float* ln1_b = (const float*)d_in[24];
  const float* f1_w = (const float*)d_in[25];
  const float* f1_b = (const float*)d_in[26];
  const float* f2_w = (const float*)d_in[27];
  const float* f2_b = (const float*)d_in[28];
  const float* ln2_g = (const float*)d_in[29];
  const float* ln2_b = (const float*)d_in[30];
  const float* out_w = (const float*)d_in[31];
  const float* out_b = (const float*)d_in[32];
  const int* x = (const int*)d_in[33];
  const int* ea = (const int*)d_in[34];
  const int* ei = (const int*)d_in[35];

  // ---- workspace map (~245 MiB total; aliased by liveness)
  char* wbase = (char*)d_ws;
  size_t woff = 0;
  auto ALLOC = [&](size_t bytes) -> void* {
    void* r = wbase + woff;
    woff += (bytes + 255) & ~(size_t)255;
    return r;
  };
  const size_t ND = (size_t)N_NODES * DIM * sizeof(float);    // 64 MiB
  const size_t NDH = (size_t)N_NODES * DIM * sizeof(u16);     // 32 MiB
  u16*   wt     = (u16*)ALLOC((size_t)17825792 * sizeof(u16));  // 34 MiB weights bf16
  u16*   hb     = (u16*)ALLOC(NDH);   // residual h (bf16)
  u16*   Abuf   = (u16*)ALLOC(NDH);   // gconv q / agg-out / tlayer q / attn-O / FF chunk
  u16*   Bbuf   = (u16*)ALLOC(NDH);   // k
  u16*   Cbuf   = (u16*)ALLOC(NDH);   // gconv v / tlayer V^T
  float* E      = (float*)ALLOC(ND);  // gconv skip f32 -> pre-LN tmp f32
  u16*   U      = (u16*)ALLOC((size_t)16777216);  // logits f32 (16MiB) | S/P bf16 per 128-z round
  u16*   tab    = (u16*)ALLOC(24 * DIM * sizeof(u16));
  float* pooled = (float*)ALLOC((size_t)NG * DIM * sizeof(float));
  int* deg      = (int*)ALLOC(N_NODES * sizeof(int));
  int* cur      = (int*)ALLOC(N_NODES * sizeof(int));
  int* rp       = (int*)ALLOC((N_NODES + 1) * sizeof(int));
  int* csr      = (int*)ALLOC((size_t)NE * sizeof(int));
  (void)ws_size; (void)in_sizes; (void)n_in; (void)out_size;

  const size_t DD = (size_t)DIM * DIM;
  const size_t DD4 = 4 * DD;
  u16* gqT = wt;            u16* gkT = wt + DD4;      u16* gvT = wt + 2 * DD4;
  u16* gskipT = wt + 3*DD4; u16* midT = wt + 4 * DD4;
  u16* tqT = wt + 5 * DD4;  u16* tkT = wt + 6 * DD4;  u16* tvT = wt + 7 * DD4;
  u16* toT = wt + 8 * DD4;
  u16* f1T = wt + 9 * DD4;
  u16* f2T = f1T + (size_t)4 * DIM * FF_;

  auto wcvt = [&](const float* W, u16* Wt, int K, int N, int L2) {
    dim3 grid(N / 32, K / 32, L2);
    wcvt_kernel<<<grid, 256, 0, stream>>>(W, Wt, K, N);
  };
  auto mgemm = [&](const u16* A_, const u16* Bt_, const float* bias_,
                   float* Cf_, u16* Cb_, int M_, int K_, int Nout_,
                   int relu_, int bf16o_, int vtout_) {
    dim3 grid(Nout_ / 128, M_ / 128);
    gemm_mfma_kernel<<<grid, 256, 0, stream>>>(A_, Bt_, bias_, Cf_, Cb_, K_, Nout_, relu_, bf16o_, vtout_);
  };

  // ---- weight convert/transpose
  wcvt(gq_w, gqT, DIM, DIM, 4);   wcvt(gk_w, gkT, DIM, DIM, 4);
  wcvt(gv_w, gvT, DIM, DIM, 4);   wcvt(gskip_w, gskipT, DIM, DIM, 4);
  wcvt(mid_w, midT, DIM, DIM, 4);
  wcvt(tq_w, tqT, DIM, DIM, 4);   wcvt(tk_w, tkT, DIM, DIM, 4);
  wcvt(tv_w, tvT, DIM, DIM, 4);   wcvt(to_w, toT, DIM, DIM, 4);
  wcvt(f1_w, f1T, DIM, FF_, 4);   wcvt(f2_w, f2T, FF_, DIM, 4);

  // ---- CSR build
  hipMemsetAsync(deg, 0, N_NODES * sizeof(int), stream);
  hipMemsetAsync(cur, 0, N_NODES * sizeof(int), stream);
  deg_count_kernel<<<NE / 256, 256, 0, stream>>>(ei, deg);
  scan_kernel<<<1, 1024, 0, stream>>>(deg, rp);
  scatter_kernel<<<NE / 256, 256, 0, stream>>>(ei, rp, cur, csr);

  // ---- encoder
  atom_enc_kernel<<<N_NODES, 128, 0, stream>>>(atom_emb, x, hb);

  // ---- graph-conv layers
  for (int i = 0; i < NL; ++i) {
    bemb_proj_kernel<<<dim3(24, 8), 512, 0, stream>>>(bond_emb, ge_w + i * DD, tab);
    mgemm(hb, gqT + i * DD, gq_b + i * DIM, nullptr, Abuf, N_NODES, DIM, DIM, 0, 1, 0);   // q bf16
    mgemm(hb, gkT + i * DD, gk_b + i * DIM, nullptr, Bbuf, N_NODES, DIM, DIM, 0, 1, 0);   // k bf16
    mgemm(hb, gvT + i * DD, gv_b + i * DIM, nullptr, Cbuf, N_NODES, DIM, DIM, 0, 1, 0);   // v bf16
    mgemm(hb, gskipT + i * DD, gskip_b + i * DIM, E, nullptr, N_NODES, DIM, DIM, 0, 0, 0); // skip f32
    edge_logits_kernel<<<NE / 4, 256, 0, stream>>>(Abuf, Bbuf, tab, ei, ea, (float*)U);
    edge_agg_kernel<<<N_NODES, 512, 0, stream>>>(Cbuf, tab, (float*)U, E, ei, ea, rp, csr, Abuf);
    mgemm(Abuf, midT + i * DD, mid_b + i * DIM, E, nullptr, N_NODES, DIM, DIM, 0, 0, 0);
    ln_kernel<<<N_NODES / 4, 256, 0, stream>>>(E, nullptr, mid_g + i * DIM, mid_bt + i * DIM, hb, 1);
  }

  // ---- transformer layers
  for (int i = 0; i < NL; ++i) {
    mgemm(hb, tqT + i * DD, tq_b + i * DIM, nullptr, Abuf, N_NODES, DIM, DIM, 0, 1, 0);   // q bf16
    mgemm(hb, tkT + i * DD, tk_b + i * DIM, nullptr, Bbuf, N_NODES, DIM, DIM, 0, 1, 0);   // k bf16
    mgemm(hb, tvT + i * DD, tv_b + i * DIM, nullptr, Cbuf, N_NODES, DIM, DIM, 0, 1, 1);   // V^T bf16
    for (int rnd = 0; rnd < 4; ++rnd) {   // 128 (g,h)-slices per round; S/P in 16MiB U
      attn_s_mfma_kernel<<<dim3(2, 2, 128), 256, 0, stream>>>(Abuf, Bbuf, U, rnd * 128);
      softmax256_kernel<<<(128 * NPG_) / 4, 256, 0, stream>>>(U);
      attn_o_mfma_kernel<<<dim3(1, 2, 128), 256, 0, stream>>>(U, Cbuf, Abuf, rnd * 128);
    }
    mgemm(Abuf, toT + i * DD, to_b + i * DIM, E, nullptr, N_NODES, DIM, DIM, 0, 0, 0);
    ln_kernel<<<N_NODES / 4, 256, 0, stream>>>(E, hb, ln1_g + i * DIM, ln1_b + i * DIM, hb, 0);
    for (int c = 0; c < 4; ++c) {         // FF in 4 row-chunks of 8192 through Abuf
      mgemm(hb + (size_t)c * 8192 * DIM, f1T + (size_t)i * DIM * FF_, f1_b + i * FF_,
            nullptr, Abuf, 8192, DIM, FF_, 1, 1, 0);
      mgemm(Abuf, f2T + (size_t)i * FF_ * DIM, f2_b + i * DIM,
            E + (size_t)c * 8192 * DIM, nullptr, 8192, FF_, DIM, 0, 0, 0);
    }
    ln_kernel<<<N_NODES / 4, 256, 0, stream>>>(E, hb, ln2_g + i * DIM, ln2_b + i * DIM, hb, 0);
  }

  // ---- readout
  pool_kernel<<<NG, 512, 0, stream>>>(hb, pooled);
  gemm_bias_kernel<<<dim3(OUTD / 64, NG / 64), 256, 0, stream>>>(pooled, out_w, out_b, (float*)d_out, NG, DIM, OUTD, 0);
}